// Round 7
// baseline (5982.042 us; speedup 1.0000x reference)
//
#include <hip/hip_runtime.h>
#include <hip/hip_bf16.h>
#include <math.h>

#define L_ 4096
#define B_ 4
#define D_ 1024
#define Z_ 128
#define H_ 2048
#define NN_ 16
#define C_ 256
#define NMX_ (Z_ + H_ + 2*D_)   // 4224
#define CLEN_ 256               // EMA chunk length (== C_)
#define BDCH_ (B_*D_)           // 4096 channels, c = b*D + d

typedef __hip_bfloat16 bf16;
__device__ __forceinline__ float b2f(bf16 v){ return __bfloat162float(v); }
__device__ __forceinline__ bf16  f2b(float v){ return __float2bfloat16(v); }
__device__ __forceinline__ float sigmoidf_(float x){ return 1.0f/(1.0f+expf(-x)); }
__device__ __forceinline__ float siluf_(float x){ return x/(1.0f+expf(-x)); }

// ---------------- zero the EMA state (d_ws is 0xAA-poisoned every call) ----
__global__ __launch_bounds__(256) void init_state(float* __restrict__ st){
  st[blockIdx.x*256 + threadIdx.x] = 0.f;   // 256 blocks -> 65536 floats
}

// ---------------- LayerNorm (f32 -> bf16), one row per block -------------
__global__ __launch_bounds__(256) void ln_kernel(const float* __restrict__ x,
    const float* __restrict__ w, const float* __restrict__ b, bf16* __restrict__ xn){
  int row = blockIdx.x; int tid = threadIdx.x;
  const float* xr = x + (size_t)row * D_;
  float4 v = reinterpret_cast<const float4*>(xr)[tid];
  float s  = v.x+v.y+v.z+v.w;
  float ss = v.x*v.x + v.y*v.y + v.z*v.z + v.w*v.w;
  __shared__ float rs[256], rss[256];
  rs[tid]=s; rss[tid]=ss; __syncthreads();
  for(int st=128; st>0; st>>=1){
    if(tid<st){ rs[tid]+=rs[tid+st]; rss[tid]+=rss[tid+st]; }
    __syncthreads();
  }
  float mu = rs[0]*(1.0f/D_);
  float var = rss[0]*(1.0f/D_) - mu*mu;
  float inv = rsqrtf(var + 1e-5f);
  int d0 = tid*4;
  bf16* o = xn + (size_t)row*D_ + d0;
  o[0] = f2b((v.x-mu)*inv*w[d0+0]+b[d0+0]);
  o[1] = f2b((v.y-mu)*inv*w[d0+1]+b[d0+1]);
  o[2] = f2b((v.z-mu)*inv*w[d0+2]+b[d0+2]);
  o[3] = f2b((v.w-mu)*inv*w[d0+3]+b[d0+3]);
}

// ---------------- EMA pass1: per-chunk local end-states -------------------
// grid (16, CHs): c = bx*256+tid in [0,4096), ch = by
__global__ __launch_bounds__(256) void ema_pass1(const bf16* __restrict__ xn,
    const float* __restrict__ e_delta, const float* __restrict__ e_alpha,
    float* __restrict__ send){
  int c = blockIdx.x*256 + threadIdx.x;
  int ch = blockIdx.y;
  int d = c & (D_-1);
  float q[NN_], s[NN_];
  #pragma unroll
  for(int n=0;n<NN_;n++){
    float p = sigmoidf_(e_delta[d*NN_+n]);
    float a = sigmoidf_(e_alpha[d*NN_+n]);
    q[n] = 1.0f - p*a; s[n]=0.f;
  }
  const bf16* xp = xn + (size_t)ch*CLEN_*BDCH_ + c;
  for(int l=0;l<CLEN_;l++){
    float xv = b2f(xp[(size_t)l*BDCH_]);
    #pragma unroll
    for(int n=0;n<NN_;n++) s[n] = fmaf(q[n], s[n], xv);
  }
  float* sp = send + ((size_t)ch*BDCH_ + c)*NN_;
  #pragma unroll
  for(int n=0;n<NN_;n++) sp[n]=s[n];
}

// ---------------- EMA pass2: combine carries + update global state --------
// 65536 threads: t = c*16+n
__global__ __launch_bounds__(256) void ema_pass2(const float* __restrict__ e_delta,
    const float* __restrict__ e_alpha, const float* __restrict__ send,
    float* __restrict__ carry, float* __restrict__ state, int CHs){
  int t = blockIdx.x*256 + threadIdx.x;
  int n = t & (NN_-1); int c = t >> 4; int d = c & (D_-1);
  float p = sigmoidf_(e_delta[d*NN_+n]);
  float a = sigmoidf_(e_alpha[d*NN_+n]);
  float q = 1.0f - p*a;
  float qC = exp2f((float)CLEN_ * log2f(q));
  float cy = state[t];               // state at start of this slab
  carry[t] = cy;
  for(int ch=1; ch<CHs; ch++){
    cy = fmaf(qC, cy, send[(size_t)(ch-1)*65536 + t]);
    carry[(size_t)ch*65536 + t] = cy;
  }
  state[t] = fmaf(qC, cy, send[(size_t)(CHs-1)*65536 + t]);  // slab-end state
}

// ---------------- EMA pass3: rescan with carries, fuse silu gate ----------
__global__ __launch_bounds__(256) void ema_pass3(const bf16* __restrict__ xn,
    const float* __restrict__ e_delta, const float* __restrict__ e_alpha,
    const float* __restrict__ e_beta, const float* __restrict__ e_gamma,
    const float* __restrict__ e_omega, const float* __restrict__ carry,
    bf16* __restrict__ mx){
  int c = blockIdx.x*256 + threadIdx.x;
  int ch = blockIdx.y;
  int d = c & (D_-1);
  float q[NN_], w[NN_], s[NN_];
  #pragma unroll
  for(int n=0;n<NN_;n++){
    float p = sigmoidf_(e_delta[d*NN_+n]);
    float a = sigmoidf_(e_alpha[d*NN_+n]);
    q[n] = 1.0f - p*a;
    w[n] = p * e_beta[d*NN_+n] * (e_gamma[d*NN_+n] * 0.25f);  // EMA_SCALE=(1/16)^.5
    s[n] = carry[(size_t)ch*65536 + c*16 + n];
  }
  float om = e_omega[d];
  const bf16* xp = xn + (size_t)ch*CLEN_*BDCH_ + c;
  bf16* mp = mx + (size_t)ch*CLEN_*BDCH_ + c;
  for(int l=0;l<CLEN_;l++){
    float xv = b2f(xp[(size_t)l*BDCH_]);
    float conv = 0.f;
    #pragma unroll
    for(int n=0;n<NN_;n++){ s[n] = fmaf(q[n], s[n], xv); conv = fmaf(w[n], s[n], conv); }
    mp[(size_t)l*BDCH_] = f2b(siluf_(conv + xv*om));
  }
}

// ---------------- GEMM, 64x64 tile, 4x4/thread, f32 accum, A=bf16 ---------
// EPI 0: out_bf = bf16 silu(acc+bias)                       (v)
// EPI 1: route base cols into u(f32,d_out)/z(f32)/r,hx(bf16)
// EPI 2: out_f = x + u*(silu(hx+acc+hb)-x)   [uin aliases out_f: same-elem RMW]
template<int EPI>
__global__ __launch_bounds__(256) void gemm_kernel(
    const bf16* __restrict__ A, const float* __restrict__ Bw,
    int M, int N, int K, const float* __restrict__ bias,
    bf16* __restrict__ out_bf,
    float* o_u, float* __restrict__ o_z,
    bf16* __restrict__ o_r, bf16* __restrict__ o_hx,
    float* out_f, const float* __restrict__ xin, const float* uin,
    const bf16* __restrict__ hxin, const float* __restrict__ hb){
  __shared__ float As[16][65];
  __shared__ float Bs[16][65];
  const int tid = threadIdx.x;
  const int tx = tid & 15, ty = tid >> 4;
  const int n0 = blockIdx.x * 64, m0 = blockIdx.y * 64;
  const int kk = tid & 15, mm = tid >> 4;   // A-load coords
  const int nn = tid & 63, kq = tid >> 6;   // B-load coords
  float acc[4][4] = {};
  for (int k0 = 0; k0 < K; k0 += 16) {
    #pragma unroll
    for (int r2 = 0; r2 < 4; r2++) {
      size_t aidx = (size_t)(m0 + mm + 16*r2) * K + (k0 + kk);
      As[kk][mm + 16*r2] = b2f(A[aidx]);
    }
    #pragma unroll
    for (int r2 = 0; r2 < 4; r2++) {
      Bs[kq + 4*r2][nn] = Bw[(size_t)(k0 + kq + 4*r2) * N + (n0 + nn)];
    }
    __syncthreads();
    #pragma unroll
    for (int k = 0; k < 16; k++) {
      float a0 = As[k][ty*4+0], a1 = As[k][ty*4+1], a2 = As[k][ty*4+2], a3 = As[k][ty*4+3];
      float b0 = Bs[k][tx*4+0], b1 = Bs[k][tx*4+1], b2 = Bs[k][tx*4+2], b3 = Bs[k][tx*4+3];
      acc[0][0]=fmaf(a0,b0,acc[0][0]); acc[0][1]=fmaf(a0,b1,acc[0][1]);
      acc[0][2]=fmaf(a0,b2,acc[0][2]); acc[0][3]=fmaf(a0,b3,acc[0][3]);
      acc[1][0]=fmaf(a1,b0,acc[1][0]); acc[1][1]=fmaf(a1,b1,acc[1][1]);
      acc[1][2]=fmaf(a1,b2,acc[1][2]); acc[1][3]=fmaf(a1,b3,acc[1][3]);
      acc[2][0]=fmaf(a2,b0,acc[2][0]); acc[2][1]=fmaf(a2,b1,acc[2][1]);
      acc[2][2]=fmaf(a2,b2,acc[2][2]); acc[2][3]=fmaf(a2,b3,acc[2][3]);
      acc[3][0]=fmaf(a3,b0,acc[3][0]); acc[3][1]=fmaf(a3,b1,acc[3][1]);
      acc[3][2]=fmaf(a3,b2,acc[3][2]); acc[3][3]=fmaf(a3,b3,acc[3][3]);
    }
    __syncthreads();
  }
  #pragma unroll
  for (int i = 0; i < 4; i++) {
    int row = m0 + ty*4 + i;
    #pragma unroll
    for (int j = 0; j < 4; j++) {
      int col = n0 + tx*4 + j;
      float val = acc[i][j];
      if (EPI == 0) {
        out_bf[(size_t)row*N + col] = f2b(siluf_(val + bias[col]));
      } else if (EPI == 1) {
        val += bias[col];
        if (col < D_)            o_u [(size_t)row*D_ + col]              = sigmoidf_(val);
        else if (col < D_+Z_)    o_z [(size_t)row*Z_ + (col-D_)]         = siluf_(val);
        else if (col < D_+Z_+H_) o_r [(size_t)row*H_ + (col-D_-Z_)]      = f2b(siluf_(val));
        else                     o_hx[(size_t)row*D_ + (col-D_-Z_-H_)]   = f2b(val);
      } else {
        size_t oi = (size_t)row*D_ + col;
        float uv = uin[oi];                       // read BEFORE write (same elem)
        float g  = val + b2f(hxin[oi]) + hb[col];
        float hh = siluf_(g);
        float xv = xin[oi];
        out_f[oi] = xv + uv*(hh - xv);
      }
    }
  }
}

// ---------------- q/k prep: (l*B+b, Z) -> (b, l, Z) per slab --------------
__global__ __launch_bounds__(256) void qk_prep(const float* __restrict__ zbuf,
    const float* __restrict__ gamma, const float* __restrict__ beta,
    float* __restrict__ qb, float* __restrict__ kb, int LS){
  int t = blockIdx.x*256 + threadIdx.x;     // MS*Z_ threads
  int zc = t & (Z_-1); int row = t >> 7;    // row = l*B+b (slab-local)
  int l = row >> 2; int b = row & 3;
  float zv = zbuf[t];
  size_t qi = ((size_t)b*LS + l)*Z_ + zc;
  qb[qi] = (zv*gamma[zc] + beta[zc]) * 0.08838834764831845f;  // Z^-0.5
  kb[qi] = zv*gamma[Z_+zc] + beta[Z_+zc];
}

// ---------------- fused attention; h*r written in-place into r ------------
// grid (16, CHs, B): x = 16-row tile, y = chunk in slab, z = batch
__global__ __launch_bounds__(256) void attn_kernel(const float* __restrict__ qb,
    const float* __restrict__ kb, const bf16* __restrict__ vbuf,
    const float* __restrict__ rel_b, bf16* rbuf, int LS){
  __shared__ float qs[16][128];
  __shared__ float ks[32][129];
  __shared__ float S[16][256];
  __shared__ float red[16][17];
  int rt = blockIdx.x; int n = blockIdx.y; int b = blockIdx.z;
  int i0 = rt*16;
  int tid = threadIdx.x;
  const size_t qbase = ((size_t)b*LS + n*C_ + i0)*Z_;
  #pragma unroll
  for (int e=0;e<8;e++){ int idx = e*256+tid; qs[idx>>7][idx&127] = qb[qbase + idx]; }
  for (int kt=0; kt<8; kt++){
    __syncthreads();
    const size_t kbase = ((size_t)b*LS + n*C_ + kt*32)*Z_;
    #pragma unroll
    for (int e=0;e<16;e++){ int idx=e*256+tid; ks[idx>>7][idx&127] = kb[kbase+idx]; }
    __syncthreads();
    #pragma unroll
    for (int p=0;p<2;p++){
      int idx = p*256+tid; int r = idx>>5; int kc = idx&31;
      float acc=0.f;
      #pragma unroll 4
      for (int zc=0;zc<128;zc++) acc = fmaf(qs[r][zc], ks[kc][zc], acc);
      int kg = kt*32+kc;
      S[r][kg] = acc + rel_b[C_-1 + kg - (i0+r)];
    }
  }
  __syncthreads();
  // softmax: 16 threads per row
  int r = tid>>4, j = tid&15;
  float mxv = -1e30f;
  #pragma unroll
  for (int e=0;e<16;e++) mxv = fmaxf(mxv, S[r][j+16*e]);
  red[r][j]=mxv; __syncthreads();
  for (int st=8; st; st>>=1){ if(j<st) red[r][j]=fmaxf(red[r][j],red[r][j+st]); __syncthreads(); }
  mxv = red[r][0]; __syncthreads();
  float sm=0.f;
  #pragma unroll
  for (int e=0;e<16;e++){ float ev = expf(S[r][j+16*e]-mxv); S[r][j+16*e]=ev; sm+=ev; }
  red[r][j]=sm; __syncthreads();
  for (int st=8; st; st>>=1){ if(j<st) red[r][j]+=red[r][j+st]; __syncthreads(); }
  float inv = 1.0f/red[r][0];
  #pragma unroll
  for (int e=0;e<16;e++) S[r][j+16*e] *= inv;
  __syncthreads();
  // PV: each thread owns one h-col per pass; multiply by r in-place
  for (int hc=0; hc<8; hc++){
    int col = hc*256 + tid;
    float acc[16];
    #pragma unroll
    for (int r2=0;r2<16;r2++) acc[r2]=0.f;
    for (int tb=0; tb<64; tb++){
      int t0 = tb*4;
      float v0 = b2f(vbuf[((size_t)(n*C_+t0+0)*B_ + b)*H_ + col]);
      float v1 = b2f(vbuf[((size_t)(n*C_+t0+1)*B_ + b)*H_ + col]);
      float v2 = b2f(vbuf[((size_t)(n*C_+t0+2)*B_ + b)*H_ + col]);
      float v3 = b2f(vbuf[((size_t)(n*C_+t0+3)*B_ + b)*H_ + col]);
      #pragma unroll
      for (int r2=0;r2<16;r2++){
        float4 s4 = *reinterpret_cast<const float4*>(&S[r2][t0]);
        acc[r2] = fmaf(s4.x, v0, acc[r2]);
        acc[r2] = fmaf(s4.y, v1, acc[r2]);
        acc[r2] = fmaf(s4.z, v2, acc[r2]);
        acc[r2] = fmaf(s4.w, v3, acc[r2]);
      }
    }
    #pragma unroll
    for (int r2=0;r2<16;r2++){
      size_t idx = ((size_t)(n*C_ + i0 + r2)*B_ + b)*H_ + col;
      float rv = b2f(rbuf[idx]);
      rbuf[idx] = f2b(acc[r2]*rv);     // h*r in place; unique owner thread
    }
  }
}

extern "C" void kernel_launch(void* const* d_in, const int* in_sizes, int n_in,
                              void* d_out, int out_size, void* d_ws, size_t ws_size,
                              hipStream_t stream) {
  const float* x      = (const float*)d_in[0];
  const float* ln_w   = (const float*)d_in[1];
  const float* ln_b   = (const float*)d_in[2];
  const float* v_w    = (const float*)d_in[3];
  const float* v_b    = (const float*)d_in[4];
  const float* mx_w   = (const float*)d_in[5];
  const float* mx_b   = (const float*)d_in[6];
  const float* h_w    = (const float*)d_in[7];
  const float* h_b    = (const float*)d_in[8];
  const float* gamma  = (const float*)d_in[9];
  const float* beta   = (const float*)d_in[10];
  const float* rel_b  = (const float*)d_in[11];
  const float* e_delta= (const float*)d_in[12];
  const float* e_alpha= (const float*)d_in[13];
  const float* e_beta = (const float*)d_in[14];
  const float* e_gamma= (const float*)d_in[15];
  const float* e_omega= (const float*)d_in[16];
  float* out = (float*)d_out;

  // ---- choose slab count P from ws_size (P constant across calls) ----
  int P = 16;
  for (int p = 1; p <= 16; p <<= 1) {
    size_t LSp = L_/p, MSp = LSp*B_;
    size_t need = MSp*D_*2*3           // xn, mx, hx (bf16)
                + MSp*H_*2*2           // v, r (bf16)
                + LSp*2048             // send+carry (f32) == z (f32) alias
                + 262144               // EMA state
                + (1u<<20);            // slack
    if (need + (size_t)(16u<<20) <= ws_size) { P = p; break; }
  }
  const size_t LS = L_/P, MS = LS*B_;
  const int CHs = (int)(LS/CLEN_);

  // ---- per-slab arena ----
  char* a = (char*)d_ws;
  bf16* xn   = (bf16*)a;  a += MS*D_*2;
  bf16* mx   = (bf16*)a;  a += MS*D_*2;
  bf16* vb   = (bf16*)a;  a += MS*H_*2;
  bf16* rb   = (bf16*)a;  a += MS*H_*2;
  bf16* hx   = (bf16*)a;  a += MS*D_*2;
  float* send = (float*)a;                  // [CHs][4096][16]
  float* zb   = (float*)a;  a += LS*2048;   // z aliases send+carry (post-EMA)
  float* carry= send + (size_t)CHs*BDCH_*NN_;
  float* state= (float*)a;  a += 262144;
  float* qb   = (float*)xn;                 // q,k alias xn (dead after gemm0)
  float* kb   = qb + MS*Z_;

  init_state<<<256, 256, 0, stream>>>(state);

  for (int s = 0; s < P; s++) {
    const size_t r0 = (size_t)s * MS;       // global row offset of slab
    const float* xs   = x   + r0*D_;
    float*       outs = out + r0*D_;

    ln_kernel<<<(int)MS, 256, 0, stream>>>(xs, ln_w, ln_b, xn);
    ema_pass1<<<dim3(16, CHs), 256, 0, stream>>>(xn, e_delta, e_alpha, send);
    ema_pass2<<<256, 256, 0, stream>>>(e_delta, e_alpha, send, carry, state, CHs);
    ema_pass3<<<dim3(16, CHs), 256, 0, stream>>>(xn, e_delta, e_alpha,
        e_beta, e_gamma, e_omega, carry, mx);
    gemm_kernel<0><<<dim3(H_/64, (int)(MS/64)), 256, 0, stream>>>(
        xn, v_w, (int)MS, H_, D_, v_b, vb,
        nullptr, nullptr, nullptr, nullptr, nullptr, nullptr, nullptr, nullptr, nullptr);
    gemm_kernel<1><<<dim3(NMX_/64, (int)(MS/64)), 256, 0, stream>>>(
        mx, mx_w, (int)MS, NMX_, D_, mx_b, nullptr,
        outs /*u*/, zb, rb, hx, nullptr, nullptr, nullptr, nullptr, nullptr);
    qk_prep<<<(int)(MS/2), 256, 0, stream>>>(zb, gamma, beta, qb, kb, (int)LS);
    attn_kernel<<<dim3(16, CHs, B_), 256, 0, stream>>>(qb, kb, vb, rel_b, rb, (int)LS);
    gemm_kernel<2><<<dim3(D_/64, (int)(MS/64)), 256, 0, stream>>>(
        rb, h_w, (int)MS, D_, H_, nullptr, nullptr,
        nullptr, nullptr, nullptr, nullptr,
        outs, xs, outs /*u*/, hx, h_b);
  }
}

// Round 8
// 1462.917 us; speedup vs baseline: 4.0891x; 4.0891x over previous
//
#include <hip/hip_runtime.h>
#include <hip/hip_bf16.h>
#include <math.h>

#define L_ 4096
#define B_ 4
#define D_ 1024
#define Z_ 128
#define H_ 2048
#define NN_ 16
#define C_ 256
#define NMX_ (Z_ + H_ + 2*D_)   // 4224
#define CLEN_ 256               // EMA chunk length (== C_)
#define BDCH_ (B_*D_)           // 4096 channels, c = b*D + d

typedef __hip_bfloat16 bf16;
typedef __bf16 bf16x8 __attribute__((ext_vector_type(8)));
typedef float  f32x4  __attribute__((ext_vector_type(4)));
__device__ __forceinline__ float b2f(bf16 v){ return __bfloat162float(v); }
__device__ __forceinline__ bf16  f2b(float v){ return __float2bfloat16(v); }
__device__ __forceinline__ float sigmoidf_(float x){ return 1.0f/(1.0f+expf(-x)); }
__device__ __forceinline__ float siluf_(float x){ return x/(1.0f+expf(-x)); }

// ---------------- zero the EMA state (d_ws is 0xAA-poisoned every call) ----
__global__ __launch_bounds__(256) void init_state(float* __restrict__ st){
  st[blockIdx.x*256 + threadIdx.x] = 0.f;   // 256 blocks -> 65536 floats
}

// ---------------- weight transpose+convert: W[K][N] f32 -> Wt[N][K] bf16 --
__global__ __launch_bounds__(256) void wcvt(const float* __restrict__ W,
    bf16* __restrict__ Wt, int K, int N){
  __shared__ float tle[32][33];
  int k0 = blockIdx.x*32, n0 = blockIdx.y*32;
  int tx = threadIdx.x & 31, ty = threadIdx.x >> 5;   // 8 rows/pass
  #pragma unroll
  for (int i=0;i<4;i++){ int r = ty + i*8; tle[r][tx] = W[(size_t)(k0+r)*N + n0+tx]; }
  __syncthreads();
  #pragma unroll
  for (int i=0;i<4;i++){ int r = ty + i*8; Wt[(size_t)(n0+r)*K + k0+tx] = f2b(tle[tx][r]); }
}

// ---------------- LayerNorm (f32 -> bf16), one row per block -------------
__global__ __launch_bounds__(256) void ln_kernel(const float* __restrict__ x,
    const float* __restrict__ w, const float* __restrict__ b, bf16* __restrict__ xn){
  int row = blockIdx.x; int tid = threadIdx.x;
  const float* xr = x + (size_t)row * D_;
  float4 v = reinterpret_cast<const float4*>(xr)[tid];
  float s  = v.x+v.y+v.z+v.w;
  float ss = v.x*v.x + v.y*v.y + v.z*v.z + v.w*v.w;
  __shared__ float rs[256], rss[256];
  rs[tid]=s; rss[tid]=ss; __syncthreads();
  for(int st=128; st>0; st>>=1){
    if(tid<st){ rs[tid]+=rs[tid+st]; rss[tid]+=rss[tid+st]; }
    __syncthreads();
  }
  float mu = rs[0]*(1.0f/D_);
  float var = rss[0]*(1.0f/D_) - mu*mu;
  float inv = rsqrtf(var + 1e-5f);
  int d0 = tid*4;
  bf16* o = xn + (size_t)row*D_ + d0;
  o[0] = f2b((v.x-mu)*inv*w[d0+0]+b[d0+0]);
  o[1] = f2b((v.y-mu)*inv*w[d0+1]+b[d0+1]);
  o[2] = f2b((v.z-mu)*inv*w[d0+2]+b[d0+2]);
  o[3] = f2b((v.w-mu)*inv*w[d0+3]+b[d0+3]);
}

// ---------------- EMA pass1: per-chunk local end-states -------------------
__global__ __launch_bounds__(256) void ema_pass1(const bf16* __restrict__ xn,
    const float* __restrict__ e_delta, const float* __restrict__ e_alpha,
    float* __restrict__ send){
  int c = blockIdx.x*256 + threadIdx.x;
  int ch = blockIdx.y;
  int d = c & (D_-1);
  float q[NN_], s[NN_];
  #pragma unroll
  for(int n=0;n<NN_;n++){
    float p = sigmoidf_(e_delta[d*NN_+n]);
    float a = sigmoidf_(e_alpha[d*NN_+n]);
    q[n] = 1.0f - p*a; s[n]=0.f;
  }
  const bf16* xp = xn + (size_t)ch*CLEN_*BDCH_ + c;
  for(int l=0;l<CLEN_;l++){
    float xv = b2f(xp[(size_t)l*BDCH_]);
    #pragma unroll
    for(int n=0;n<NN_;n++) s[n] = fmaf(q[n], s[n], xv);
  }
  float* sp = send + ((size_t)ch*BDCH_ + c)*NN_;
  #pragma unroll
  for(int n=0;n<NN_;n++) sp[n]=s[n];
}

// ---------------- EMA pass2: combine carries + update global state --------
__global__ __launch_bounds__(256) void ema_pass2(const float* __restrict__ e_delta,
    const float* __restrict__ e_alpha, const float* __restrict__ send,
    float* __restrict__ carry, float* __restrict__ state, int CHs){
  int t = blockIdx.x*256 + threadIdx.x;
  int n = t & (NN_-1); int c = t >> 4; int d = c & (D_-1);
  float p = sigmoidf_(e_delta[d*NN_+n]);
  float a = sigmoidf_(e_alpha[d*NN_+n]);
  float q = 1.0f - p*a;
  float qC = exp2f((float)CLEN_ * log2f(q));
  float cy = state[t];               // state at start of this slab
  carry[t] = cy;
  for(int ch=1; ch<CHs; ch++){
    cy = fmaf(qC, cy, send[(size_t)(ch-1)*65536 + t]);
    carry[(size_t)ch*65536 + t] = cy;
  }
  state[t] = fmaf(qC, cy, send[(size_t)(CHs-1)*65536 + t]);  // slab-end state
}

// ---------------- EMA pass3: rescan with carries, fuse silu gate ----------
__global__ __launch_bounds__(256) void ema_pass3(const bf16* __restrict__ xn,
    const float* __restrict__ e_delta, const float* __restrict__ e_alpha,
    const float* __restrict__ e_beta, const float* __restrict__ e_gamma,
    const float* __restrict__ e_omega, const float* __restrict__ carry,
    bf16* __restrict__ mx){
  int c = blockIdx.x*256 + threadIdx.x;
  int ch = blockIdx.y;
  int d = c & (D_-1);
  float q[NN_], w[NN_], s[NN_];
  #pragma unroll
  for(int n=0;n<NN_;n++){
    float p = sigmoidf_(e_delta[d*NN_+n]);
    float a = sigmoidf_(e_alpha[d*NN_+n]);
    q[n] = 1.0f - p*a;
    w[n] = p * e_beta[d*NN_+n] * (e_gamma[d*NN_+n] * 0.25f);  // EMA_SCALE=(1/16)^.5
    s[n] = carry[(size_t)ch*65536 + c*16 + n];
  }
  float om = e_omega[d];
  const bf16* xp = xn + (size_t)ch*CLEN_*BDCH_ + c;
  bf16* mp = mx + (size_t)ch*CLEN_*BDCH_ + c;
  for(int l=0;l<CLEN_;l++){
    float xv = b2f(xp[(size_t)l*BDCH_]);
    float conv = 0.f;
    #pragma unroll
    for(int n=0;n<NN_;n++){ s[n] = fmaf(q[n], s[n], xv); conv = fmaf(w[n], s[n], conv); }
    mp[(size_t)l*BDCH_] = f2b(siluf_(conv + xv*om));
  }
}

// ---------------- bf16 MFMA GEMM: 128x128 tile, 4 waves, BK=32 ------------
// A[M][K] bf16 row-major; Bt[N][K] bf16 row-major (pre-transposed weights).
// EPI 0: out_bf = bf16 silu(acc+bias)                       (v)
// EPI 1: route base cols into u(f32,d_out)/z(f32)/r,hx(bf16)
// EPI 2: out_f = x + u*(silu(hx+acc+hb)-x)   [uin aliases out_f: same-elem RMW]
#define LDSTR 40   // bf16 row stride: 80B -> fragment reads spread all 8 bank groups
template<int EPI>
__global__ __launch_bounds__(256) void gemm_kernel(
    const bf16* __restrict__ Ap, const bf16* __restrict__ Btp,
    int M, int N, int K, const float* __restrict__ bias,
    bf16* __restrict__ out_bf,
    float* o_u, float* __restrict__ o_z,
    bf16* __restrict__ o_r, bf16* __restrict__ o_hx,
    float* out_f, const float* __restrict__ xin, const float* uin,
    const bf16* __restrict__ hxin, const float* __restrict__ hb){
  __shared__ __bf16 As[128*LDSTR];
  __shared__ __bf16 Bs[128*LDSTR];
  const __bf16* A  = reinterpret_cast<const __bf16*>(Ap);
  const __bf16* Bt = reinterpret_cast<const __bf16*>(Btp);
  const int t = threadIdx.x;
  const int n0 = blockIdx.x * 128, m0 = blockIdx.y * 128;
  const int lane = t & 63, wv = t >> 6;
  const int wr = (wv >> 1) * 64, wc = (wv & 1) * 64;
  const int lr = lane & 15, kg = (lane >> 4) * 8, rg = (lane >> 4) * 4;
  f32x4 acc[4][4] = {};
  for (int kb = 0; kb < K; kb += 32) {
    #pragma unroll
    for (int h = 0; h < 2; h++) {
      int c = t + h*256;              // 512 chunks of 8 bf16 per tile
      int row = c >> 2, off = (c & 3) * 8;
      *reinterpret_cast<bf16x8*>(&As[row*LDSTR + off]) =
          *reinterpret_cast<const bf16x8*>(A  + (size_t)(m0+row)*K + kb + off);
      *reinterpret_cast<bf16x8*>(&Bs[row*LDSTR + off]) =
          *reinterpret_cast<const bf16x8*>(Bt + (size_t)(n0+row)*K + kb + off);
    }
    __syncthreads();
    bf16x8 af[4], bfr[4];
    #pragma unroll
    for (int m=0;m<4;m++) af[m]  = *reinterpret_cast<const bf16x8*>(&As[(wr+m*16+lr)*LDSTR + kg]);
    #pragma unroll
    for (int n=0;n<4;n++) bfr[n] = *reinterpret_cast<const bf16x8*>(&Bs[(wc+n*16+lr)*LDSTR + kg]);
    #pragma unroll
    for (int m=0;m<4;m++)
      #pragma unroll
      for (int n=0;n<4;n++)
        acc[m][n] = __builtin_amdgcn_mfma_f32_16x16x32_bf16(af[m], bfr[n], acc[m][n], 0,0,0);
    __syncthreads();
  }
  #pragma unroll
  for (int m=0;m<4;m++){
    #pragma unroll
    for (int n=0;n<4;n++){
      f32x4 v = acc[m][n];
      #pragma unroll
      for (int r=0;r<4;r++){
        int row = m0 + wr + m*16 + rg + r;
        int col = n0 + wc + n*16 + lr;
        float val = v[r];
        if (EPI == 0) {
          out_bf[(size_t)row*N + col] = f2b(siluf_(val + bias[col]));
        } else if (EPI == 1) {
          val += bias[col];
          if (col < D_)            o_u [(size_t)row*D_ + col]              = sigmoidf_(val);
          else if (col < D_+Z_)    o_z [(size_t)row*Z_ + (col-D_)]         = siluf_(val);
          else if (col < D_+Z_+H_) o_r [(size_t)row*H_ + (col-D_-Z_)]      = f2b(siluf_(val));
          else                     o_hx[(size_t)row*D_ + (col-D_-Z_-H_)]   = f2b(val);
        } else {
          size_t oi = (size_t)row*D_ + col;
          float uv = uin[oi];                       // read BEFORE write (same elem)
          float g  = val + b2f(hxin[oi]) + hb[col];
          float hh = siluf_(g);
          float xv = xin[oi];
          out_f[oi] = xv + uv*(hh - xv);
        }
      }
    }
  }
}

// ---------------- q/k prep: (l*B+b, Z) -> (b, l, Z) per slab --------------
__global__ __launch_bounds__(256) void qk_prep(const float* __restrict__ zbuf,
    const float* __restrict__ gamma, const float* __restrict__ beta,
    float* __restrict__ qb, float* __restrict__ kb, int LS){
  int t = blockIdx.x*256 + threadIdx.x;     // MS*Z_ threads
  int zc = t & (Z_-1); int row = t >> 7;    // row = l*B+b (slab-local)
  int l = row >> 2; int b = row & 3;
  float zv = zbuf[t];
  size_t qi = ((size_t)b*LS + l)*Z_ + zc;
  qb[qi] = (zv*gamma[zc] + beta[zc]) * 0.08838834764831845f;  // Z^-0.5
  kb[qi] = zv*gamma[Z_+zc] + beta[Z_+zc];
}

// ---------------- fused attention; h*r written in-place into r ------------
__global__ __launch_bounds__(256) void attn_kernel(const float* __restrict__ qb,
    const float* __restrict__ kb, const bf16* __restrict__ vbuf,
    const float* __restrict__ rel_b, bf16* rbuf, int LS){
  __shared__ float qs[16][128];
  __shared__ float ks[32][129];
  __shared__ float S[16][256];
  __shared__ float red[16][17];
  int rt = blockIdx.x; int n = blockIdx.y; int b = blockIdx.z;
  int i0 = rt*16;
  int tid = threadIdx.x;
  const size_t qbase = ((size_t)b*LS + n*C_ + i0)*Z_;
  #pragma unroll
  for (int e=0;e<8;e++){ int idx = e*256+tid; qs[idx>>7][idx&127] = qb[qbase + idx]; }
  for (int kt=0; kt<8; kt++){
    __syncthreads();
    const size_t kbase = ((size_t)b*LS + n*C_ + kt*32)*Z_;
    #pragma unroll
    for (int e=0;e<16;e++){ int idx=e*256+tid; ks[idx>>7][idx&127] = kb[kbase+idx]; }
    __syncthreads();
    #pragma unroll
    for (int p=0;p<2;p++){
      int idx = p*256+tid; int r = idx>>5; int kc = idx&31;
      float acc=0.f;
      #pragma unroll 4
      for (int zc=0;zc<128;zc++) acc = fmaf(qs[r][zc], ks[kc][zc], acc);
      int kg = kt*32+kc;
      S[r][kg] = acc + rel_b[C_-1 + kg - (i0+r)];
    }
  }
  __syncthreads();
  int r = tid>>4, j = tid&15;
  float mxv = -1e30f;
  #pragma unroll
  for (int e=0;e<16;e++) mxv = fmaxf(mxv, S[r][j+16*e]);
  red[r][j]=mxv; __syncthreads();
  for (int st=8; st; st>>=1){ if(j<st) red[r][j]=fmaxf(red[r][j],red[r][j+st]); __syncthreads(); }
  mxv = red[r][0]; __syncthreads();
  float sm=0.f;
  #pragma unroll
  for (int e=0;e<16;e++){ float ev = expf(S[r][j+16*e]-mxv); S[r][j+16*e]=ev; sm+=ev; }
  red[r][j]=sm; __syncthreads();
  for (int st=8; st; st>>=1){ if(j<st) red[r][j]+=red[r][j+st]; __syncthreads(); }
  float inv = 1.0f/red[r][0];
  #pragma unroll
  for (int e=0;e<16;e++) S[r][j+16*e] *= inv;
  __syncthreads();
  for (int hc=0; hc<8; hc++){
    int col = hc*256 + tid;
    float acc[16];
    #pragma unroll
    for (int r2=0;r2<16;r2++) acc[r2]=0.f;
    for (int tb=0; tb<64; tb++){
      int t0 = tb*4;
      float v0 = b2f(vbuf[((size_t)(n*C_+t0+0)*B_ + b)*H_ + col]);
      float v1 = b2f(vbuf[((size_t)(n*C_+t0+1)*B_ + b)*H_ + col]);
      float v2 = b2f(vbuf[((size_t)(n*C_+t0+2)*B_ + b)*H_ + col]);
      float v3 = b2f(vbuf[((size_t)(n*C_+t0+3)*B_ + b)*H_ + col]);
      #pragma unroll
      for (int r2=0;r2<16;r2++){
        float4 s4 = *reinterpret_cast<const float4*>(&S[r2][t0]);
        acc[r2] = fmaf(s4.x, v0, acc[r2]);
        acc[r2] = fmaf(s4.y, v1, acc[r2]);
        acc[r2] = fmaf(s4.z, v2, acc[r2]);
        acc[r2] = fmaf(s4.w, v3, acc[r2]);
      }
    }
    #pragma unroll
    for (int r2=0;r2<16;r2++){
      size_t idx = ((size_t)(n*C_ + i0 + r2)*B_ + b)*H_ + col;
      float rv = b2f(rbuf[idx]);
      rbuf[idx] = f2b(acc[r2]*rv);     // h*r in place; unique owner thread
    }
  }
}

extern "C" void kernel_launch(void* const* d_in, const int* in_sizes, int n_in,
                              void* d_out, int out_size, void* d_ws, size_t ws_size,
                              hipStream_t stream) {
  const float* x      = (const float*)d_in[0];
  const float* ln_w   = (const float*)d_in[1];
  const float* ln_b   = (const float*)d_in[2];
  const float* v_w    = (const float*)d_in[3];
  const float* v_b    = (const float*)d_in[4];
  const float* mx_w   = (const float*)d_in[5];
  const float* mx_b   = (const float*)d_in[6];
  const float* h_w    = (const float*)d_in[7];
  const float* h_b    = (const float*)d_in[8];
  const float* gamma  = (const float*)d_in[9];
  const float* beta   = (const float*)d_in[10];
  const float* rel_b  = (const float*)d_in[11];
  const float* e_delta= (const float*)d_in[12];
  const float* e_alpha= (const float*)d_in[13];
  const float* e_beta = (const float*)d_in[14];
  const float* e_gamma= (const float*)d_in[15];
  const float* e_omega= (const float*)d_in[16];
  float* out = (float*)d_out;

  // bf16 transposed weights (persist whole call): 17,039,360 B
  const size_t WB = ((size_t)H_*D_ + (size_t)NMX_*D_ + (size_t)D_*H_) * 2;

  // ---- choose slab count P from ws_size (P constant across calls) ----
  int P = 16;
  for (int p = 1; p <= 16; p <<= 1) {
    size_t LSp = L_/p, MSp = LSp*B_;
    size_t need = WB
                + MSp*D_*2*3           // xn, mx, hx (bf16)
                + MSp*H_*2*2           // v, r (bf16)
                + LSp*2048             // send+carry (f32) == z (f32) alias
                + 262144               // EMA state
                + (1u<<20);            // slack
    if (need + (size_t)(16u<<20) <= ws_size) { P = p; break; }
  }
  const size_t LS = L_/P, MS = LS*B_;
  const int CHs = (int)(LS/CLEN_);

  // ---- arena ----
  char* a = (char*)d_ws;
  bf16* v_wt  = (bf16*)a;  a += (size_t)H_*D_*2;     // [H][D]  (N=2048,K=1024)
  bf16* mx_wt = (bf16*)a;  a += (size_t)NMX_*D_*2;   // [NMX][D]
  bf16* h_wt  = (bf16*)a;  a += (size_t)D_*H_*2;     // [D][H]  (N=1024,K=2048)
  bf16* xn   = (bf16*)a;  a += MS*D_*2;
  bf16* mx   = (bf16*)a;  a += MS*D_*2;
  bf16* vb   = (bf16*)a;  a += MS*H_*2;
  bf16* rb   = (bf16*)a;  a += MS*H_*2;
  bf16* hx   = (bf16*)a;  a += MS*D_*2;
  float* send = (float*)a;                  // [CHs][4096][16]
  float* zb   = (float*)a;  a += LS*2048;   // z aliases send+carry (post-EMA)
  float* carry= send + (size_t)CHs*BDCH_*NN_;
  float* state= (float*)a;  a += 262144;
  float* qb   = (float*)xn;                 // q,k alias xn (dead after gemm0)
  float* kb   = qb + MS*Z_;

  // one-time weight transpose+convert
  wcvt<<<dim3(D_/32, H_/32),   256, 0, stream>>>(v_w,  v_wt,  D_, H_);
  wcvt<<<dim3(D_/32, NMX_/32), 256, 0, stream>>>(mx_w, mx_wt, D_, NMX_);
  wcvt<<<dim3(H_/32, D_/32),   256, 0, stream>>>(h_w,  h_wt,  H_, D_);
  init_state<<<256, 256, 0, stream>>>(state);

  for (int s = 0; s < P; s++) {
    const size_t r0 = (size_t)s * MS;       // global row offset of slab
    const float* xs   = x   + r0*D_;
    float*       outs = out + r0*D_;

    ln_kernel<<<(int)MS, 256, 0, stream>>>(xs, ln_w, ln_b, xn);
    ema_pass1<<<dim3(16, CHs), 256, 0, stream>>>(xn, e_delta, e_alpha, send);
    ema_pass2<<<256, 256, 0, stream>>>(e_delta, e_alpha, send, carry, state, CHs);
    ema_pass3<<<dim3(16, CHs), 256, 0, stream>>>(xn, e_delta, e_alpha,
        e_beta, e_gamma, e_omega, carry, mx);
    gemm_kernel<0><<<dim3(H_/128, (int)(MS/128)), 256, 0, stream>>>(
        xn, v_wt, (int)MS, H_, D_, v_b, vb,
        nullptr, nullptr, nullptr, nullptr, nullptr, nullptr, nullptr, nullptr, nullptr);
    gemm_kernel<1><<<dim3(NMX_/128, (int)(MS/128)), 256, 0, stream>>>(
        mx, mx_wt, (int)MS, NMX_, D_, mx_b, nullptr,
        outs /*u*/, zb, rb, hx, nullptr, nullptr, nullptr, nullptr, nullptr);
    qk_prep<<<(int)(MS/2), 256, 0, stream>>>(zb, gamma, beta, qb, kb, (int)LS);
    attn_kernel<<<dim3(16, CHs, B_), 256, 0, stream>>>(qb, kb, vb, rel_b, rb, (int)LS);
    gemm_kernel<2><<<dim3(D_/128, (int)(MS/128)), 256, 0, stream>>>(
        rb, h_wt, (int)MS, D_, H_, nullptr, nullptr,
        nullptr, nullptr, nullptr, nullptr,
        outs, xs, outs /*u*/, hx, h_b);
  }
}

// Round 9
// 1137.888 us; speedup vs baseline: 5.2571x; 1.2856x over previous
//
#include <hip/hip_runtime.h>
#include <hip/hip_bf16.h>
#include <math.h>

#define L_ 4096
#define B_ 4
#define D_ 1024
#define Z_ 128
#define H_ 2048
#define NN_ 16
#define C_ 256
#define NMX_ (Z_ + H_ + 2*D_)   // 4224
#define CLEN_ 256               // EMA chunk length (== C_)
#define BDCH_ (B_*D_)           // 4096 channels, c = b*D + d

typedef __hip_bfloat16 bf16;
typedef __bf16 bf16x8 __attribute__((ext_vector_type(8)));
typedef float  f32x4  __attribute__((ext_vector_type(4)));
__device__ __forceinline__ float b2f(bf16 v){ return __bfloat162float(v); }
__device__ __forceinline__ bf16  f2b(float v){ return __float2bfloat16(v); }
__device__ __forceinline__ float sigmoidf_(float x){ return 1.0f/(1.0f+expf(-x)); }
__device__ __forceinline__ float siluf_(float x){ return x/(1.0f+expf(-x)); }

// ---------------- zero the EMA state (d_ws is 0xAA-poisoned every call) ----
__global__ __launch_bounds__(256) void init_state(float* __restrict__ st){
  st[blockIdx.x*256 + threadIdx.x] = 0.f;   // 256 blocks -> 65536 floats
}

// ---------------- weight transpose+convert: W[K][N] f32 -> Wt[N][K] bf16 --
__global__ __launch_bounds__(256) void wcvt(const float* __restrict__ W,
    bf16* __restrict__ Wt, int K, int N){
  __shared__ float tle[32][33];
  int k0 = blockIdx.x*32, n0 = blockIdx.y*32;
  int tx = threadIdx.x & 31, ty = threadIdx.x >> 5;   // 8 rows/pass
  #pragma unroll
  for (int i=0;i<4;i++){ int r = ty + i*8; tle[r][tx] = W[(size_t)(k0+r)*N + n0+tx]; }
  __syncthreads();
  #pragma unroll
  for (int i=0;i<4;i++){ int r = ty + i*8; Wt[(size_t)(n0+r)*K + k0+tx] = f2b(tle[tx][r]); }
}

// ---------------- LayerNorm (f32 -> bf16), one row per block -------------
__global__ __launch_bounds__(256) void ln_kernel(const float* __restrict__ x,
    const float* __restrict__ w, const float* __restrict__ b, bf16* __restrict__ xn){
  int row = blockIdx.x; int tid = threadIdx.x;
  const float* xr = x + (size_t)row * D_;
  float4 v = reinterpret_cast<const float4*>(xr)[tid];
  float s  = v.x+v.y+v.z+v.w;
  float ss = v.x*v.x + v.y*v.y + v.z*v.z + v.w*v.w;
  __shared__ float rs[256], rss[256];
  rs[tid]=s; rss[tid]=ss; __syncthreads();
  for(int st=128; st>0; st>>=1){
    if(tid<st){ rs[tid]+=rs[tid+st]; rss[tid]+=rss[tid+st]; }
    __syncthreads();
  }
  float mu = rs[0]*(1.0f/D_);
  float var = rss[0]*(1.0f/D_) - mu*mu;
  float inv = rsqrtf(var + 1e-5f);
  int d0 = tid*4;
  bf16* o = xn + (size_t)row*D_ + d0;
  o[0] = f2b((v.x-mu)*inv*w[d0+0]+b[d0+0]);
  o[1] = f2b((v.y-mu)*inv*w[d0+1]+b[d0+1]);
  o[2] = f2b((v.z-mu)*inv*w[d0+2]+b[d0+2]);
  o[3] = f2b((v.w-mu)*inv*w[d0+3]+b[d0+3]);
}

// ---------------- EMA pass1: per-chunk local end-states -------------------
__global__ __launch_bounds__(256) void ema_pass1(const bf16* __restrict__ xn,
    const float* __restrict__ e_delta, const float* __restrict__ e_alpha,
    float* __restrict__ send){
  int c = blockIdx.x*256 + threadIdx.x;
  int ch = blockIdx.y;
  int d = c & (D_-1);
  float q[NN_], s[NN_];
  #pragma unroll
  for(int n=0;n<NN_;n++){
    float p = sigmoidf_(e_delta[d*NN_+n]);
    float a = sigmoidf_(e_alpha[d*NN_+n]);
    q[n] = 1.0f - p*a; s[n]=0.f;
  }
  const bf16* xp = xn + (size_t)ch*CLEN_*BDCH_ + c;
  for(int l=0;l<CLEN_;l++){
    float xv = b2f(xp[(size_t)l*BDCH_]);
    #pragma unroll
    for(int n=0;n<NN_;n++) s[n] = fmaf(q[n], s[n], xv);
  }
  float* sp = send + ((size_t)ch*BDCH_ + c)*NN_;
  #pragma unroll
  for(int n=0;n<NN_;n++) sp[n]=s[n];
}

// ---------------- EMA pass2: combine carries + update global state --------
__global__ __launch_bounds__(256) void ema_pass2(const float* __restrict__ e_delta,
    const float* __restrict__ e_alpha, const float* __restrict__ send,
    float* __restrict__ carry, float* __restrict__ state, int CHs){
  int t = blockIdx.x*256 + threadIdx.x;
  int n = t & (NN_-1); int c = t >> 4; int d = c & (D_-1);
  float p = sigmoidf_(e_delta[d*NN_+n]);
  float a = sigmoidf_(e_alpha[d*NN_+n]);
  float q = 1.0f - p*a;
  float qC = exp2f((float)CLEN_ * log2f(q));
  float cy = state[t];               // state at start of this slab
  carry[t] = cy;
  for(int ch=1; ch<CHs; ch++){
    cy = fmaf(qC, cy, send[(size_t)(ch-1)*65536 + t]);
    carry[(size_t)ch*65536 + t] = cy;
  }
  state[t] = fmaf(qC, cy, send[(size_t)(CHs-1)*65536 + t]);  // slab-end state
}

// ---------------- EMA pass3: rescan with carries, fuse silu gate ----------
__global__ __launch_bounds__(256) void ema_pass3(const bf16* __restrict__ xn,
    const float* __restrict__ e_delta, const float* __restrict__ e_alpha,
    const float* __restrict__ e_beta, const float* __restrict__ e_gamma,
    const float* __restrict__ e_omega, const float* __restrict__ carry,
    bf16* __restrict__ mx){
  int c = blockIdx.x*256 + threadIdx.x;
  int ch = blockIdx.y;
  int d = c & (D_-1);
  float q[NN_], w[NN_], s[NN_];
  #pragma unroll
  for(int n=0;n<NN_;n++){
    float p = sigmoidf_(e_delta[d*NN_+n]);
    float a = sigmoidf_(e_alpha[d*NN_+n]);
    q[n] = 1.0f - p*a;
    w[n] = p * e_beta[d*NN_+n] * (e_gamma[d*NN_+n] * 0.25f);  // EMA_SCALE=(1/16)^.5
    s[n] = carry[(size_t)ch*65536 + c*16 + n];
  }
  float om = e_omega[d];
  const bf16* xp = xn + (size_t)ch*CLEN_*BDCH_ + c;
  bf16* mp = mx + (size_t)ch*CLEN_*BDCH_ + c;
  for(int l=0;l<CLEN_;l++){
    float xv = b2f(xp[(size_t)l*BDCH_]);
    float conv = 0.f;
    #pragma unroll
    for(int n=0;n<NN_;n++){ s[n] = fmaf(q[n], s[n], xv); conv = fmaf(w[n], s[n], conv); }
    mp[(size_t)l*BDCH_] = f2b(siluf_(conv + xv*om));
  }
}

// ---------------- bf16 MFMA GEMM: 128x128 tile, 4 waves, BK=32 ------------
#define LDSTR 40   // bf16 row stride: 80B -> fragment reads spread bank groups
template<int EPI>
__global__ __launch_bounds__(256) void gemm_kernel(
    const bf16* __restrict__ Ap, const bf16* __restrict__ Btp,
    int M, int N, int K, const float* __restrict__ bias,
    bf16* __restrict__ out_bf,
    float* o_u, float* __restrict__ o_z,
    bf16* __restrict__ o_r, bf16* __restrict__ o_hx,
    float* out_f, const float* __restrict__ xin, const float* uin,
    const bf16* __restrict__ hxin, const float* __restrict__ hb){
  __shared__ __bf16 As[128*LDSTR];
  __shared__ __bf16 Bs[128*LDSTR];
  const __bf16* A  = reinterpret_cast<const __bf16*>(Ap);
  const __bf16* Bt = reinterpret_cast<const __bf16*>(Btp);
  const int t = threadIdx.x;
  const int n0 = blockIdx.x * 128, m0 = blockIdx.y * 128;
  const int lane = t & 63, wv = t >> 6;
  const int wr = (wv >> 1) * 64, wc = (wv & 1) * 64;
  const int lr = lane & 15, kg = (lane >> 4) * 8, rg = (lane >> 4) * 4;
  f32x4 acc[4][4] = {};
  for (int kb = 0; kb < K; kb += 32) {
    #pragma unroll
    for (int h = 0; h < 2; h++) {
      int c = t + h*256;              // 512 chunks of 8 bf16 per tile
      int row = c >> 2, off = (c & 3) * 8;
      *reinterpret_cast<bf16x8*>(&As[row*LDSTR + off]) =
          *reinterpret_cast<const bf16x8*>(A  + (size_t)(m0+row)*K + kb + off);
      *reinterpret_cast<bf16x8*>(&Bs[row*LDSTR + off]) =
          *reinterpret_cast<const bf16x8*>(Bt + (size_t)(n0+row)*K + kb + off);
    }
    __syncthreads();
    bf16x8 af[4], bfr[4];
    #pragma unroll
    for (int m=0;m<4;m++) af[m]  = *reinterpret_cast<const bf16x8*>(&As[(wr+m*16+lr)*LDSTR + kg]);
    #pragma unroll
    for (int n=0;n<4;n++) bfr[n] = *reinterpret_cast<const bf16x8*>(&Bs[(wc+n*16+lr)*LDSTR + kg]);
    #pragma unroll
    for (int m=0;m<4;m++)
      #pragma unroll
      for (int n=0;n<4;n++)
        acc[m][n] = __builtin_amdgcn_mfma_f32_16x16x32_bf16(af[m], bfr[n], acc[m][n], 0,0,0);
    __syncthreads();
  }
  #pragma unroll
  for (int m=0;m<4;m++){
    #pragma unroll
    for (int n=0;n<4;n++){
      f32x4 v = acc[m][n];
      #pragma unroll
      for (int r=0;r<4;r++){
        int row = m0 + wr + m*16 + rg + r;
        int col = n0 + wc + n*16 + lr;
        float val = v[r];
        if (EPI == 0) {
          out_bf[(size_t)row*N + col] = f2b(siluf_(val + bias[col]));
        } else if (EPI == 1) {
          val += bias[col];
          if (col < D_)            o_u [(size_t)row*D_ + col]              = sigmoidf_(val);
          else if (col < D_+Z_)    o_z [(size_t)row*Z_ + (col-D_)]         = siluf_(val);
          else if (col < D_+Z_+H_) o_r [(size_t)row*H_ + (col-D_-Z_)]      = f2b(siluf_(val));
          else                     o_hx[(size_t)row*D_ + (col-D_-Z_-H_)]   = f2b(val);
        } else {
          size_t oi = (size_t)row*D_ + col;
          float uv = uin[oi];                       // read BEFORE write (same elem)
          float g  = val + b2f(hxin[oi]) + hb[col];
          float hh = siluf_(g);
          float xv = xin[oi];
          out_f[oi] = xv + uv*(hh - xv);
        }
      }
    }
  }
}

// ---------------- q/k prep: (l*B+b, Z) -> (b, l, Z) per slab --------------
__global__ __launch_bounds__(256) void qk_prep(const float* __restrict__ zbuf,
    const float* __restrict__ gamma, const float* __restrict__ beta,
    float* __restrict__ qb, float* __restrict__ kb, int LS){
  int t = blockIdx.x*256 + threadIdx.x;     // MS*Z_ threads
  int zc = t & (Z_-1); int row = t >> 7;    // row = l*B+b (slab-local)
  int l = row >> 2; int b = row & 3;
  float zv = zbuf[t];
  size_t qi = ((size_t)b*LS + l)*Z_ + zc;
  qb[qi] = (zv*gamma[zc] + beta[zc]) * 0.08838834764831845f;  // Z^-0.5
  kb[qi] = zv*gamma[Z_+zc] + beta[Z_+zc];
}

// ---------------- fused attention: scalar QK^T + MFMA PV ------------------
// grid (16, CHs, B). LDS phases: {qs,ks} (QK) then Vt (PV) share one union.
#define VTS 264   // Vt/Sb k-stride in bf16 (256 + 8 pad; 528B, 16B-aligned)
__global__ __launch_bounds__(256) void attn_kernel(const float* __restrict__ qb,
    const float* __restrict__ kb, const bf16* __restrict__ vbuf,
    const float* __restrict__ rel_b, bf16* rbuf, int LS){
  __shared__ __align__(16) char ulds[33792];        // max(qs+ks, Vt)
  __shared__ float S[16][256];
  __shared__ __bf16 Sb[16][VTS];
  __shared__ float red[16][17];
  float (*qs)[128] = reinterpret_cast<float(*)[128]>(ulds);          // 8KB
  float (*ks)[129] = reinterpret_cast<float(*)[129]>(ulds + 8192);   // 16.5KB
  __bf16 (*Vt)[VTS] = reinterpret_cast<__bf16(*)[VTS]>(ulds);        // 33.8KB
  const __bf16* vraw = reinterpret_cast<const __bf16*>(vbuf);

  int rt = blockIdx.x; int n = blockIdx.y; int b = blockIdx.z;
  int i0 = rt*16;
  int tid = threadIdx.x;
  const int lane = tid & 63, wv = tid >> 6;
  const int lr = lane & 15, kg = (lane >> 4) * 8, rg = (lane >> 4) * 4;

  // ---- QK^T (scalar f32, unchanged) ----
  const size_t qbase = ((size_t)b*LS + n*C_ + i0)*Z_;
  #pragma unroll
  for (int e=0;e<8;e++){ int idx = e*256+tid; qs[idx>>7][idx&127] = qb[qbase + idx]; }
  for (int kt=0; kt<8; kt++){
    __syncthreads();
    const size_t kbase = ((size_t)b*LS + n*C_ + kt*32)*Z_;
    #pragma unroll
    for (int e=0;e<16;e++){ int idx=e*256+tid; ks[idx>>7][idx&127] = kb[kbase+idx]; }
    __syncthreads();
    #pragma unroll
    for (int p=0;p<2;p++){
      int idx = p*256+tid; int r = idx>>5; int kc = idx&31;
      float acc=0.f;
      #pragma unroll 4
      for (int zc=0;zc<128;zc++) acc = fmaf(qs[r][zc], ks[kc][zc], acc);
      int kgl = kt*32+kc;
      S[r][kgl] = acc + rel_b[C_-1 + kgl - (i0+r)];
    }
  }
  __syncthreads();
  // ---- softmax (16 threads per row) ----
  int r = tid>>4, j = tid&15;
  float mxv = -1e30f;
  #pragma unroll
  for (int e=0;e<16;e++) mxv = fmaxf(mxv, S[r][j+16*e]);
  red[r][j]=mxv; __syncthreads();
  for (int st=8; st; st>>=1){ if(j<st) red[r][j]=fmaxf(red[r][j],red[r][j+st]); __syncthreads(); }
  mxv = red[r][0]; __syncthreads();
  float sm=0.f;
  #pragma unroll
  for (int e=0;e<16;e++){ float ev = expf(S[r][j+16*e]-mxv); S[r][j+16*e]=ev; sm+=ev; }
  red[r][j]=sm; __syncthreads();
  for (int st=8; st; st>>=1){ if(j<st) red[r][j]+=red[r][j+st]; __syncthreads(); }
  float inv = 1.0f/red[r][0];
  #pragma unroll
  for (int e=0;e<16;e++) S[r][j+16*e] *= inv;
  __syncthreads();
  // ---- S -> bf16 ----
  #pragma unroll
  for (int e=0;e<16;e++){ int col = (tid&15)*16 + e; Sb[tid>>4][col] = (__bf16)f2b(S[tid>>4][col]); }
  __syncthreads();
  // ---- hoist S fragments (shared by all 4 waves) ----
  bf16x8 afr[8];
  #pragma unroll
  for (int kb=0;kb<8;kb++) afr[kb] = *reinterpret_cast<const bf16x8*>(&Sb[lr][kb*32 + kg]);

  // ---- PV via MFMA over 64-col V chunks ----
  const int col_l = tid & 63, kg8 = tid >> 6;   // staging coords
  for (int hc = 0; hc < 32; hc++) {
    // stage Vt[64][256] = V[k][hc*64+col]^T  (coalesced global, b128 LDS writes)
    #pragma unroll
    for (int it=0; it<8; it++){
      int k0 = kg8*8 + it*32;
      bf16x8 rv;
      #pragma unroll
      for (int jj=0; jj<8; jj++){
        rv[jj] = vraw[((size_t)(n*C_ + k0 + jj)*B_ + b)*H_ + hc*64 + col_l];
      }
      *reinterpret_cast<bf16x8*>(&Vt[col_l][k0]) = rv;
    }
    __syncthreads();
    // wave wv computes 16x16 tile at cols hc*64 + wv*16
    f32x4 acc = {0.f,0.f,0.f,0.f};
    #pragma unroll
    for (int kb=0;kb<8;kb++){
      bf16x8 bfr = *reinterpret_cast<const bf16x8*>(&Vt[wv*16 + lr][kb*32 + kg]);
      acc = __builtin_amdgcn_mfma_f32_16x16x32_bf16(afr[kb], bfr, acc, 0,0,0);
    }
    #pragma unroll
    for (int rr=0;rr<4;rr++){
      int row = i0 + rg + rr;
      int col = hc*64 + wv*16 + lr;
      size_t idx = ((size_t)(n*C_ + row)*B_ + b)*H_ + col;
      float rv2 = b2f(rbuf[idx]);
      rbuf[idx] = f2b(acc[rr]*rv2);    // h*r in place; unique owner
    }
    __syncthreads();
  }
}

extern "C" void kernel_launch(void* const* d_in, const int* in_sizes, int n_in,
                              void* d_out, int out_size, void* d_ws, size_t ws_size,
                              hipStream_t stream) {
  const float* x      = (const float*)d_in[0];
  const float* ln_w   = (const float*)d_in[1];
  const float* ln_b   = (const float*)d_in[2];
  const float* v_w    = (const float*)d_in[3];
  const float* v_b    = (const float*)d_in[4];
  const float* mx_w   = (const float*)d_in[5];
  const float* mx_b   = (const float*)d_in[6];
  const float* h_w    = (const float*)d_in[7];
  const float* h_b    = (const float*)d_in[8];
  const float* gamma  = (const float*)d_in[9];
  const float* beta   = (const float*)d_in[10];
  const float* rel_b  = (const float*)d_in[11];
  const float* e_delta= (const float*)d_in[12];
  const float* e_alpha= (const float*)d_in[13];
  const float* e_beta = (const float*)d_in[14];
  const float* e_gamma= (const float*)d_in[15];
  const float* e_omega= (const float*)d_in[16];
  float* out = (float*)d_out;

  const size_t WB = ((size_t)H_*D_ + (size_t)NMX_*D_ + (size_t)D_*H_) * 2;

  int P = 16;
  for (int p = 1; p <= 16; p <<= 1) {
    size_t LSp = L_/p, MSp = LSp*B_;
    size_t need = WB
                + MSp*D_*2*3           // xn, mx, hx (bf16)
                + MSp*H_*2*2           // v, r (bf16)
                + LSp*2048             // send+carry (f32) == z (f32) alias
                + 262144               // EMA state
                + (1u<<20);            // slack
    if (need + (size_t)(16u<<20) <= ws_size) { P = p; break; }
  }
  const size_t LS = L_/P, MS = LS*B_;
  const int CHs = (int)(LS/CLEN_);

  char* a = (char*)d_ws;
  bf16* v_wt  = (bf16*)a;  a += (size_t)H_*D_*2;     // [H][D]
  bf16* mx_wt = (bf16*)a;  a += (size_t)NMX_*D_*2;   // [NMX][D]
  bf16* h_wt  = (bf16*)a;  a += (size_t)D_*H_*2;     // [D][H]
  bf16* xn   = (bf16*)a;  a += MS*D_*2;
  bf16* mx   = (bf16*)a;  a += MS*D_*2;
  bf16* vb   = (bf16*)a;  a += MS*H_*2;
  bf16* rb   = (bf16*)a;  a += MS*H_*2;
  bf16* hx   = (bf16*)a;  a += MS*D_*2;
  float* send = (float*)a;                  // [CHs][4096][16]
  float* zb   = (float*)a;  a += LS*2048;   // z aliases send+carry (post-EMA)
  float* carry= send + (size_t)CHs*BDCH_*NN_;
  float* state= (float*)a;  a += 262144;
  float* qb   = (float*)xn;                 // q,k alias xn (dead after gemm0)
  float* kb   = qb + MS*Z_;

  wcvt<<<dim3(D_/32, H_/32),   256, 0, stream>>>(v_w,  v_wt,  D_, H_);
  wcvt<<<dim3(D_/32, NMX_/32), 256, 0, stream>>>(mx_w, mx_wt, D_, NMX_);
  wcvt<<<dim3(H_/32, D_/32),   256, 0, stream>>>(h_w,  h_wt,  H_, D_);
  init_state<<<256, 256, 0, stream>>>(state);

  for (int s = 0; s < P; s++) {
    const size_t r0 = (size_t)s * MS;       // global row offset of slab
    const float* xs   = x   + r0*D_;
    float*       outs = out + r0*D_;

    ln_kernel<<<(int)MS, 256, 0, stream>>>(xs, ln_w, ln_b, xn);
    ema_pass1<<<dim3(16, CHs), 256, 0, stream>>>(xn, e_delta, e_alpha, send);
    ema_pass2<<<256, 256, 0, stream>>>(e_delta, e_alpha, send, carry, state, CHs);
    ema_pass3<<<dim3(16, CHs), 256, 0, stream>>>(xn, e_delta, e_alpha,
        e_beta, e_gamma, e_omega, carry, mx);
    gemm_kernel<0><<<dim3(H_/128, (int)(MS/128)), 256, 0, stream>>>(
        xn, v_wt, (int)MS, H_, D_, v_b, vb,
        nullptr, nullptr, nullptr, nullptr, nullptr, nullptr, nullptr, nullptr, nullptr);
    gemm_kernel<1><<<dim3(NMX_/128, (int)(MS/128)), 256, 0, stream>>>(
        mx, mx_wt, (int)MS, NMX_, D_, mx_b, nullptr,
        outs /*u*/, zb, rb, hx, nullptr, nullptr, nullptr, nullptr, nullptr);
    qk_prep<<<(int)(MS/2), 256, 0, stream>>>(zb, gamma, beta, qb, kb, (int)LS);
    attn_kernel<<<dim3(16, CHs, B_), 256, 0, stream>>>(qb, kb, vb, rel_b, rb, (int)LS);
    gemm_kernel<2><<<dim3(D_/128, (int)(MS/128)), 256, 0, stream>>>(
        rb, h_wt, (int)MS, D_, H_, nullptr, nullptr,
        nullptr, nullptr, nullptr, nullptr,
        outs, xs, outs /*u*/, hx, h_b);
  }
}